// Round 1
// baseline (4676.888 us; speedup 1.0000x reference)
//
#include <hip/hip_runtime.h>
#include <math.h>

#define N_NODES 65536
#define N_EDGES 262144
#define TWIN 25
#define NVAR 4
#define EMB 128
#define N_LAYERS 6
#define T_MAX_F 16.0f
#define EPS_F 1e-5f

__device__ __forceinline__ float silu_f(float v){
    return v / (1.0f + __expf(-v));
}

// 4x4 register-tile GEMM accumulate over quads of k:
// acc[i][j] += sum_k A[r0+i][k] * W[k][c0+j], A in LDS (pitch lda), W row-major [K][128].
__device__ __forceinline__ void gemm44(const float* A, int lda, const float* __restrict__ W,
                                       int kq_begin, int kq_end, int r0, int c0, float acc[4][4]){
    for (int kq = kq_begin; kq < kq_end; ++kq){
        int k = kq * 4;
        float a[4][4], w[4][4];
        #pragma unroll
        for (int i = 0; i < 4; ++i){
            float4 v = *(const float4*)(A + (r0 + i) * lda + k);
            a[i][0] = v.x; a[i][1] = v.y; a[i][2] = v.z; a[i][3] = v.w;
        }
        #pragma unroll
        for (int kk = 0; kk < 4; ++kk){
            float4 v = *(const float4*)(W + (k + kk) * 128 + c0);
            w[kk][0] = v.x; w[kk][1] = v.y; w[kk][2] = v.z; w[kk][3] = v.w;
        }
        #pragma unroll
        for (int kk = 0; kk < 4; ++kk)
            #pragma unroll
            for (int i = 0; i < 4; ++i)
                #pragma unroll
                for (int j = 0; j < 4; ++j)
                    acc[i][j] = fmaf(a[i][kk], w[kk][j], acc[i][j]);
    }
}

// ---------------- max(pos) ----------------
__global__ __launch_bounds__(256) void k_max(const float* __restrict__ pos, unsigned* __restrict__ outmax){
    __shared__ float s[256];
    int tid = threadIdx.x;
    float m = 0.0f;  // pos is uniform(0,1): nonnegative
    for (int i = blockIdx.x * 256 + tid; i < N_NODES; i += 256 * 256)
        m = fmaxf(m, pos[i]);
    s[tid] = m;
    __syncthreads();
    for (int off = 128; off > 0; off >>= 1){
        if (tid < off) s[tid] = fmaxf(s[tid], s[tid + off]);
        __syncthreads();
    }
    if (tid == 0) atomicMax(outmax, __float_as_uint(s[0]));
}

// ---------------- degree ----------------
__global__ __launch_bounds__(256) void k_deg(const int* __restrict__ dst, int* __restrict__ deg){
    int i = blockIdx.x * 256 + threadIdx.x;
    if (i < N_EDGES) atomicAdd(deg + dst[i], 1);
}

// ---------------- p, inv_deg ----------------
__global__ __launch_bounds__(256) void k_prep(const float* __restrict__ pos, const unsigned* __restrict__ maxp,
                                              const int* __restrict__ deg,
                                              float* __restrict__ p, float* __restrict__ invdeg){
    int i = blockIdx.x * 256 + threadIdx.x;
    if (i < N_NODES){
        float mp = __uint_as_float(*maxp);
        p[i] = pos[i] / mp;
        invdeg[i] = 1.0f / fmaxf((float)deg[i], 1.0f);
    }
}

// ---------------- encoder: h = silu(silu(inp0 @ W1 + b1) @ W2 + b2) ----------------
__global__ __launch_bounds__(256) void k_enc(const float* __restrict__ x, const float* __restrict__ p,
                                             const float* __restrict__ vars,
                                             const float* __restrict__ W1, const float* __restrict__ b1,
                                             const float* __restrict__ W2, const float* __restrict__ b2,
                                             float* __restrict__ hA){
    __shared__ __align__(16) float sin_[32 * 32];   // inp0 padded 30->32
    __shared__ __align__(16) float sw1[32 * 128];   // enc_W1 padded 30->32 rows
    __shared__ __align__(16) float sy[32 * 128];    // y1
    int tid = threadIdx.x;
    int n0 = blockIdx.x * 32;
    for (int i = tid; i < 32 * 32; i += 256){
        int e = i >> 5, k = i & 31;
        int node = n0 + e;
        float v;
        if (k < 25)       v = x[node * 25 + k];
        else if (k == 25) v = p[node];
        else if (k == 26) v = vars[node * 4 + 3] * (1.0f / T_MAX_F);
        else if (k < 30)  v = vars[node * 4 + (k - 27)];
        else              v = 0.0f;
        sin_[e * 32 + k] = v;
    }
    for (int i = tid; i < 32 * 128; i += 256){
        int r = i >> 7;
        sw1[i] = (r < 30) ? W1[i] : 0.0f;
    }
    __syncthreads();
    int c0 = (tid & 31) * 4, r0 = (tid >> 5) * 4;
    float acc[4][4] = {};
    gemm44(sin_, 32, sw1, 0, 8, r0, c0, acc);
    float4 bv = *(const float4*)(b1 + c0);
    float b_[4] = {bv.x, bv.y, bv.z, bv.w};
    #pragma unroll
    for (int i = 0; i < 4; ++i){
        float4 o;
        o.x = silu_f(acc[i][0] + b_[0]);
        o.y = silu_f(acc[i][1] + b_[1]);
        o.z = silu_f(acc[i][2] + b_[2]);
        o.w = silu_f(acc[i][3] + b_[3]);
        *(float4*)(sy + (r0 + i) * 128 + c0) = o;
    }
    __syncthreads();
    float acc2[4][4] = {};
    gemm44(sy, 128, W2, 0, 32, r0, c0, acc2);
    float4 b2v = *(const float4*)(b2 + c0);
    float bb[4] = {b2v.x, b2v.y, b2v.z, b2v.w};
    #pragma unroll
    for (int i = 0; i < 4; ++i){
        float4 o;
        o.x = silu_f(acc2[i][0] + bb[0]);
        o.y = silu_f(acc2[i][1] + bb[1]);
        o.z = silu_f(acc2[i][2] + bb[2]);
        o.w = silu_f(acc2[i][3] + bb[3]);
        *(float4*)(hA + (size_t)(n0 + r0 + i) * 128 + c0) = o;
    }
}

// ---------------- edge message MLP + scatter-add ----------------
__global__ __launch_bounds__(256) void k_edge(const float* __restrict__ hA, const float* __restrict__ x,
                                              const float* __restrict__ p, const float* __restrict__ vars,
                                              const int* __restrict__ esrc, const int* __restrict__ edst,
                                              const float* __restrict__ W1, const float* __restrict__ b1,
                                              const float* __restrict__ W2, const float* __restrict__ b2,
                                              float* __restrict__ agg){
    __shared__ __align__(16) float sm[32 * 288];  // m_in [32][286 pad 288]; later overlaid by y1 [32][128]
    __shared__ int sdst[32], ssrc[32];
    int tid = threadIdx.x;
    int e0 = blockIdx.x * 32;
    if (tid < 32){ sdst[tid] = edst[e0 + tid]; ssrc[tid] = esrc[e0 + tid]; }
    __syncthreads();
    // gather h[dst] (cols 0..127) and h[src] (cols 128..255), float4-wise
    for (int i = tid; i < 32 * 64; i += 256){
        int e = i >> 6, rest = i & 63, which = rest >> 5, chunk = rest & 31;
        int node = which ? ssrc[e] : sdst[e];
        float4 v = *(const float4*)(hA + (size_t)node * 128 + chunk * 4);
        *(float4*)(sm + e * 288 + which * 128 + chunk * 4) = v;
    }
    // tail features: cols 256..287 (xdiff 25, pdiff 1, vars[dst] 4, pad 2)
    for (int i = tid; i < 32 * 32; i += 256){
        int e = i >> 5, k = i & 31;
        int d = sdst[e], s = ssrc[e];
        float v;
        if (k < 25)       v = x[d * 25 + k] - x[s * 25 + k];
        else if (k == 25) v = p[d] - p[s];
        else if (k < 30)  v = vars[d * 4 + (k - 26)];
        else              v = 0.0f;
        sm[e * 288 + 256 + k] = v;
    }
    __syncthreads();
    int c0 = (tid & 31) * 4, r0 = (tid >> 5) * 4;
    float acc[4][4] = {};
    gemm44(sm, 288, W1, 0, 71, r0, c0, acc);   // k = 0..283
    #pragma unroll
    for (int kk = 0; kk < 2; ++kk){            // tail k = 284,285
        int k = 284 + kk;
        float a[4];
        #pragma unroll
        for (int i = 0; i < 4; ++i) a[i] = sm[(r0 + i) * 288 + k];
        float4 wv = *(const float4*)(W1 + k * 128 + c0);
        float w[4] = {wv.x, wv.y, wv.z, wv.w};
        #pragma unroll
        for (int i = 0; i < 4; ++i)
            #pragma unroll
            for (int j = 0; j < 4; ++j)
                acc[i][j] = fmaf(a[i], w[j], acc[i][j]);
    }
    __syncthreads();  // all m_in reads complete before overlay
    float4 bv = *(const float4*)(b1 + c0);
    float b_[4] = {bv.x, bv.y, bv.z, bv.w};
    #pragma unroll
    for (int i = 0; i < 4; ++i){
        float4 o;
        o.x = silu_f(acc[i][0] + b_[0]);
        o.y = silu_f(acc[i][1] + b_[1]);
        o.z = silu_f(acc[i][2] + b_[2]);
        o.w = silu_f(acc[i][3] + b_[3]);
        *(float4*)(sm + (r0 + i) * 128 + c0) = o;   // y1 overlay
    }
    __syncthreads();
    float acc2[4][4] = {};
    gemm44(sm, 128, W2, 0, 32, r0, c0, acc2);
    float4 b2v = *(const float4*)(b2 + c0);
    float bb[4] = {b2v.x, b2v.y, b2v.z, b2v.w};
    #pragma unroll
    for (int i = 0; i < 4; ++i){
        int d = sdst[r0 + i];
        #pragma unroll
        for (int j = 0; j < 4; ++j){
            float v = silu_f(acc2[i][j] + bb[j]);
            atomicAdd(agg + (size_t)d * 128 + c0 + j, v);
        }
    }
}

// ---------------- node update MLP (in-place h += u) ----------------
__global__ __launch_bounds__(256) void k_upd(float* __restrict__ hA, const float* __restrict__ agg,
                                             const float* __restrict__ vars, const float* __restrict__ invdeg,
                                             const float* __restrict__ W1, const float* __restrict__ b1,
                                             const float* __restrict__ W2, const float* __restrict__ b2){
    __shared__ __align__(16) float sm[32 * 264];  // [h(128) | agg*invdeg(128) | vars(4) | pad(4)]
    __shared__ __align__(16) float sy[32 * 128];
    int tid = threadIdx.x;
    int n0 = blockIdx.x * 32;
    for (int i = tid; i < 32 * 64; i += 256){
        int e = i >> 6, rest = i & 63, which = rest >> 5, chunk = rest & 31;
        int node = n0 + e;
        float4 v;
        if (which == 0){
            v = *(const float4*)(hA + (size_t)node * 128 + chunk * 4);
        } else {
            v = *(const float4*)(agg + (size_t)node * 128 + chunk * 4);
            float s = invdeg[node];
            v.x *= s; v.y *= s; v.z *= s; v.w *= s;
        }
        *(float4*)(sm + e * 264 + which * 128 + chunk * 4) = v;
    }
    for (int i = tid; i < 32 * 8; i += 256){
        int e = i >> 3, k = i & 7;
        sm[e * 264 + 256 + k] = (k < 4) ? vars[(size_t)(n0 + e) * 4 + k] : 0.0f;
    }
    __syncthreads();
    int c0 = (tid & 31) * 4, r0 = (tid >> 5) * 4;
    float acc[4][4] = {};
    gemm44(sm, 264, W1, 0, 65, r0, c0, acc);   // K = 260 exactly
    float4 bv = *(const float4*)(b1 + c0);
    float b_[4] = {bv.x, bv.y, bv.z, bv.w};
    #pragma unroll
    for (int i = 0; i < 4; ++i){
        float4 o;
        o.x = silu_f(acc[i][0] + b_[0]);
        o.y = silu_f(acc[i][1] + b_[1]);
        o.z = silu_f(acc[i][2] + b_[2]);
        o.w = silu_f(acc[i][3] + b_[3]);
        *(float4*)(sy + (r0 + i) * 128 + c0) = o;
    }
    __syncthreads();
    float acc2[4][4] = {};
    gemm44(sy, 128, W2, 0, 32, r0, c0, acc2);
    float4 b2v = *(const float4*)(b2 + c0);
    float bb[4] = {b2v.x, b2v.y, b2v.z, b2v.w};
    #pragma unroll
    for (int i = 0; i < 4; ++i){
        float4 o;
        o.x = sm[(r0 + i) * 264 + c0 + 0] + silu_f(acc2[i][0] + bb[0]);
        o.y = sm[(r0 + i) * 264 + c0 + 1] + silu_f(acc2[i][1] + bb[1]);
        o.z = sm[(r0 + i) * 264 + c0 + 2] + silu_f(acc2[i][2] + bb[2]);
        o.w = sm[(r0 + i) * 264 + c0 + 3] + silu_f(acc2[i][3] + bb[3]);
        *(float4*)(hA + (size_t)(n0 + r0 + i) * 128 + c0) = o;
    }
}

// ---------------- layernorm stats (two-stage, deterministic) ----------------
__global__ __launch_bounds__(256) void k_stats1(const float* __restrict__ h,
                                                float* __restrict__ psum, float* __restrict__ psq){
    __shared__ float s1[256], s2[256];
    int tid = threadIdx.x;
    int c = tid & 127, half = tid >> 7;
    int rbase = blockIdx.x * 256 + half * 128;
    float s = 0.0f, q = 0.0f;
    for (int r = 0; r < 128; ++r){
        float v = h[(size_t)(rbase + r) * 128 + c];
        s += v; q += v * v;
    }
    s1[tid] = s; s2[tid] = q;
    __syncthreads();
    if (half == 0){
        psum[blockIdx.x * 128 + c] = s1[tid] + s1[tid + 128];
        psq [blockIdx.x * 128 + c] = s2[tid] + s2[tid + 128];
    }
}

__global__ __launch_bounds__(128) void k_stats2(const float* __restrict__ psum, const float* __restrict__ psq,
                                                float* __restrict__ mu, float* __restrict__ istd){
    int c = threadIdx.x;
    float s = 0.0f, q = 0.0f;
    for (int b = 0; b < 256; ++b){ s += psum[b * 128 + c]; q += psq[b * 128 + c]; }
    float m = s * (1.0f / N_NODES);
    float v = q * (1.0f / N_NODES) - m * m;
    mu[c] = m;
    istd[c] = rsqrtf(v + EPS_F);
}

__global__ __launch_bounds__(256) void k_ln(float* __restrict__ h, const float* __restrict__ mu,
                                            const float* __restrict__ istd){
    int idx = blockIdx.x * 256 + threadIdx.x;   // float4 index over N*32
    int c4 = idx & 31;
    float4 v = *(float4*)(h + (size_t)idx * 4);
    float4 m = *(const float4*)(mu + c4 * 4);
    float4 sd = *(const float4*)(istd + c4 * 4);
    v.x = (v.x - m.x) * sd.x;
    v.y = (v.y - m.y) * sd.y;
    v.z = (v.z - m.z) * sd.z;
    v.w = (v.w - m.w) * sd.w;
    *(float4*)(h + (size_t)idx * 4) = v;
}

// ---------------- decoder conv + output ----------------
__global__ __launch_bounds__(256) void k_dec(const float* __restrict__ h, const float* __restrict__ x,
                                             const float* __restrict__ dt,
                                             const float* __restrict__ W1, const float* __restrict__ b1,
                                             const float* __restrict__ W2, const float* __restrict__ b2,
                                             float* __restrict__ out){
    __shared__ __align__(16) float sh[8 * 128];
    __shared__ float so[8 * 308];   // out1: 8 ch x 38 pos, pitch 308
    __shared__ float sw1[128], sw2[112], sb1[8];
    int tid = threadIdx.x;
    int n0 = blockIdx.x * 8;
    for (int i = tid; i < 8 * 32; i += 256){
        int e = i >> 5, chunk = i & 31;
        *(float4*)(sh + e * 128 + chunk * 4) = *(const float4*)(h + (size_t)(n0 + e) * 128 + chunk * 4);
    }
    if (tid < 128) sw1[tid] = W1[tid];
    else if (tid < 240) sw2[tid - 128] = W2[tid - 128];
    if (tid < 8) sb1[tid] = b1[tid];
    __syncthreads();
    int g = tid >> 5, lane = tid & 31;
    int node = n0 + g;
    for (int idx = lane; idx < 304; idx += 32){
        int c = idx / 38, j = idx % 38;
        float a = sb1[c];
        int base = 3 * j;
        #pragma unroll
        for (int k = 0; k < 16; ++k) a = fmaf(sh[g * 128 + base + k], sw1[c * 16 + k], a);
        so[g * 308 + c * 38 + j] = silu_f(a);
    }
    __syncthreads();
    if (lane < 25){
        float a = b2[0];
        #pragma unroll
        for (int c = 0; c < 8; ++c)
            #pragma unroll
            for (int k = 0; k < 14; ++k)
                a = fmaf(so[g * 308 + c * 38 + lane + k], sw2[c * 14 + k], a);
        float dtv = dt[0];
        out[(size_t)node * 25 + lane] = x[(size_t)node * 25 + 24] + dtv * (float)(lane + 1) * a;
    }
}

extern "C" void kernel_launch(void* const* d_in, const int* in_sizes, int n_in,
                              void* d_out, int out_size, void* d_ws, size_t ws_size,
                              hipStream_t stream){
    (void)in_sizes; (void)n_in; (void)out_size; (void)ws_size;
    const float* x      = (const float*)d_in[0];
    const float* pos    = (const float*)d_in[1];
    const float* vars   = (const float*)d_in[2];
    const float* dt     = (const float*)d_in[3];
    const int*   ei     = (const int*)d_in[4];
    const float* encW1  = (const float*)d_in[5];
    const float* encb1  = (const float*)d_in[6];
    const float* encW2  = (const float*)d_in[7];
    const float* encb2  = (const float*)d_in[8];
    const float* msgW1  = (const float*)d_in[9];
    const float* msgb1  = (const float*)d_in[10];
    const float* msgW2  = (const float*)d_in[11];
    const float* msgb2  = (const float*)d_in[12];
    const float* updW1  = (const float*)d_in[13];
    const float* updb1  = (const float*)d_in[14];
    const float* updW2  = (const float*)d_in[15];
    const float* updb2  = (const float*)d_in[16];
    const float* decW1  = (const float*)d_in[17];
    const float* decb1  = (const float*)d_in[18];
    const float* decW2  = (const float*)d_in[19];
    const float* decb2  = (const float*)d_in[20];
    float* out = (float*)d_out;

    float* ws = (float*)d_ws;
    size_t off = 0;
    float* hA     = ws + off; off += (size_t)N_NODES * 128;
    float* agg    = ws + off; off += (size_t)N_NODES * 128;
    float* p      = ws + off; off += N_NODES;
    float* invdeg = ws + off; off += N_NODES;
    float* psum   = ws + off; off += 256 * 128;
    float* psq    = ws + off; off += 256 * 128;
    float* muA    = ws + off; off += 128;
    float* istdA  = ws + off; off += 128;
    int* deg      = (int*)(ws + off); off += N_NODES;
    unsigned* maxp = (unsigned*)(ws + off); off += 1;

    const int* esrc = ei;
    const int* edst = ei + N_EDGES;

    // zero deg + maxp (contiguous)
    hipMemsetAsync(deg, 0, (size_t)N_NODES * sizeof(int) + sizeof(unsigned), stream);

    k_max<<<256, 256, 0, stream>>>(pos, maxp);
    k_deg<<<N_EDGES / 256, 256, 0, stream>>>(edst, deg);
    k_prep<<<N_NODES / 256, 256, 0, stream>>>(pos, maxp, deg, p, invdeg);
    k_enc<<<N_NODES / 32, 256, 0, stream>>>(x, p, vars, encW1, encb1, encW2, encb2, hA);

    for (int l = 0; l < N_LAYERS; ++l){
        hipMemsetAsync(agg, 0, (size_t)N_NODES * 128 * sizeof(float), stream);
        k_edge<<<N_EDGES / 32, 256, 0, stream>>>(hA, x, p, vars, esrc, edst,
            msgW1 + (size_t)l * 286 * 128, msgb1 + l * 128,
            msgW2 + (size_t)l * 128 * 128, msgb2 + l * 128, agg);
        k_upd<<<N_NODES / 32, 256, 0, stream>>>(hA, agg, vars, invdeg,
            updW1 + (size_t)l * 260 * 128, updb1 + l * 128,
            updW2 + (size_t)l * 128 * 128, updb2 + l * 128);
        k_stats1<<<256, 256, 0, stream>>>(hA, psum, psq);
        k_stats2<<<1, 128, 0, stream>>>(psum, psq, muA, istdA);
        k_ln<<<8192, 256, 0, stream>>>(hA, muA, istdA);
    }

    k_dec<<<N_NODES / 8, 256, 0, stream>>>(hA, x, dt, decW1, decb1, decW2, decb2, out);
}

// Round 2
// 1458.960 us; speedup vs baseline: 3.2056x; 3.2056x over previous
//
#include <hip/hip_runtime.h>
#include <math.h>

#define N_NODES 65536
#define N_EDGES 262144
#define TWIN 25
#define NVAR 4
#define EMB 128
#define N_LAYERS 6
#define T_MAX_F 16.0f
#define EPS_F 1e-5f

typedef float  f32x4  __attribute__((ext_vector_type(4)));
typedef __bf16 bf16x8 __attribute__((ext_vector_type(8)));
typedef __bf16 bf16x4 __attribute__((ext_vector_type(4)));

__device__ __forceinline__ float silu_f(float v){
    return v / (1.0f + __expf(-v));
}

__device__ __forceinline__ f32x4 mfma16(bf16x8 a, bf16x8 b, f32x4 c){
    return __builtin_amdgcn_mfma_f32_16x16x32_bf16(a, b, c, 0, 0, 0);
}

// A-fragment-packed LDS position (halfword index) for M=32 tiles.
// Layout: [kb][mt][lane][8], lane = (row&15) | (((k&31)>>3)<<4), elem = k&7.
__device__ __forceinline__ int apos(int row, int k){
    return (((k >> 5) * 2 + (row >> 4)) * 64 + ((row & 15) | (((k >> 3) & 3) << 4))) * 8 + (k & 7);
}

// ---------------- weight prepack: f32 [K][128] -> bf16 B-fragment order ----------------
// Packed layout per weight: [kb][cb(8)][lane(64)][elem(8)], col = cb*16 + (lane&15),
// k = kb*32 + (lane>>4)*8 + elem.  Zero-pad k >= Kreal.
#define PK_MSG1 (6 * 36864)
#define PK_MSG2 (6 * 16384)
#define PK_UPD1 (6 * 36864)
#define PK_UPD2 (6 * 16384)
#define PK_TOTAL (PK_MSG1 + PK_MSG2 + PK_UPD1 + PK_UPD2)

__global__ __launch_bounds__(256) void k_pack(const float* __restrict__ msgW1, const float* __restrict__ msgW2,
                                              const float* __restrict__ updW1, const float* __restrict__ updW2,
                                              __bf16* __restrict__ out){
    int pg = blockIdx.x * 256 + threadIdx.x;
    if (pg >= PK_TOTAL) return;
    int p = pg;
    const float* W; int Kreal, perL;
    if (p < PK_MSG1){ W = msgW1; Kreal = 286; perL = 36864; }
    else if ((p -= PK_MSG1) < PK_MSG2){ W = msgW2; Kreal = 128; perL = 16384; }
    else if ((p -= PK_MSG2) < PK_UPD1){ W = updW1; Kreal = 260; perL = 36864; }
    else { p -= PK_UPD1; W = updW2; Kreal = 128; perL = 16384; }
    int l = p / perL, q = p % perL;
    int elem = q & 7, lane = (q >> 3) & 63, cb = (q >> 9) & 7, kb = q >> 12;
    int col = cb * 16 + (lane & 15);
    int k = kb * 32 + ((lane >> 4) << 3) + elem;
    float v = (k < Kreal) ? W[(size_t)l * Kreal * 128 + (size_t)k * 128 + col] : 0.0f;
    out[pg] = (__bf16)v;
}

// ---------------- max(pos) ----------------
__global__ __launch_bounds__(256) void k_max(const float* __restrict__ pos, unsigned* __restrict__ outmax){
    __shared__ float s[256];
    int tid = threadIdx.x;
    float m = 0.0f;
    for (int i = blockIdx.x * 256 + tid; i < N_NODES; i += 256 * 256)
        m = fmaxf(m, pos[i]);
    s[tid] = m;
    __syncthreads();
    for (int off = 128; off > 0; off >>= 1){
        if (tid < off) s[tid] = fmaxf(s[tid], s[tid + off]);
        __syncthreads();
    }
    if (tid == 0) atomicMax(outmax, __float_as_uint(s[0]));
}

// ---------------- degree ----------------
__global__ __launch_bounds__(256) void k_deg(const int* __restrict__ dst, int* __restrict__ deg){
    int i = blockIdx.x * 256 + threadIdx.x;
    if (i < N_EDGES) atomicAdd(deg + dst[i], 1);
}

// ---------------- p, inv_deg ----------------
__global__ __launch_bounds__(256) void k_prep(const float* __restrict__ pos, const unsigned* __restrict__ maxp,
                                              const int* __restrict__ deg,
                                              float* __restrict__ p, float* __restrict__ invdeg){
    int i = blockIdx.x * 256 + threadIdx.x;
    if (i < N_NODES){
        float mp = __uint_as_float(*maxp);
        p[i] = pos[i] / mp;
        invdeg[i] = 1.0f / fmaxf((float)deg[i], 1.0f);
    }
}

// ---------------- encoder (f32, runs once) ----------------
__device__ __forceinline__ void gemm44(const float* A, int lda, const float* __restrict__ W,
                                       int kq_begin, int kq_end, int r0, int c0, float acc[4][4]){
    for (int kq = kq_begin; kq < kq_end; ++kq){
        int k = kq * 4;
        float a[4][4], w[4][4];
        #pragma unroll
        for (int i = 0; i < 4; ++i){
            float4 v = *(const float4*)(A + (r0 + i) * lda + k);
            a[i][0] = v.x; a[i][1] = v.y; a[i][2] = v.z; a[i][3] = v.w;
        }
        #pragma unroll
        for (int kk = 0; kk < 4; ++kk){
            float4 v = *(const float4*)(W + (k + kk) * 128 + c0);
            w[kk][0] = v.x; w[kk][1] = v.y; w[kk][2] = v.z; w[kk][3] = v.w;
        }
        #pragma unroll
        for (int kk = 0; kk < 4; ++kk)
            #pragma unroll
            for (int i = 0; i < 4; ++i)
                #pragma unroll
                for (int j = 0; j < 4; ++j)
                    acc[i][j] = fmaf(a[i][kk], w[kk][j], acc[i][j]);
    }
}

__global__ __launch_bounds__(256) void k_enc(const float* __restrict__ x, const float* __restrict__ p,
                                             const float* __restrict__ vars,
                                             const float* __restrict__ W1, const float* __restrict__ b1,
                                             const float* __restrict__ W2, const float* __restrict__ b2,
                                             float* __restrict__ hA){
    __shared__ __align__(16) float sin_[32 * 32];
    __shared__ __align__(16) float sw1[32 * 128];
    __shared__ __align__(16) float sy[32 * 128];
    int tid = threadIdx.x;
    int n0 = blockIdx.x * 32;
    for (int i = tid; i < 32 * 32; i += 256){
        int e = i >> 5, k = i & 31;
        int node = n0 + e;
        float v;
        if (k < 25)       v = x[node * 25 + k];
        else if (k == 25) v = p[node];
        else if (k == 26) v = vars[node * 4 + 3] * (1.0f / T_MAX_F);
        else if (k < 30)  v = vars[node * 4 + (k - 27)];
        else              v = 0.0f;
        sin_[e * 32 + k] = v;
    }
    for (int i = tid; i < 32 * 128; i += 256){
        int r = i >> 7;
        sw1[i] = (r < 30) ? W1[i] : 0.0f;
    }
    __syncthreads();
    int c0 = (tid & 31) * 4, r0 = (tid >> 5) * 4;
    float acc[4][4] = {};
    gemm44(sin_, 32, sw1, 0, 8, r0, c0, acc);
    float4 bv = *(const float4*)(b1 + c0);
    float b_[4] = {bv.x, bv.y, bv.z, bv.w};
    #pragma unroll
    for (int i = 0; i < 4; ++i){
        float4 o;
        o.x = silu_f(acc[i][0] + b_[0]);
        o.y = silu_f(acc[i][1] + b_[1]);
        o.z = silu_f(acc[i][2] + b_[2]);
        o.w = silu_f(acc[i][3] + b_[3]);
        *(float4*)(sy + (r0 + i) * 128 + c0) = o;
    }
    __syncthreads();
    float acc2[4][4] = {};
    gemm44(sy, 128, W2, 0, 32, r0, c0, acc2);
    float4 b2v = *(const float4*)(b2 + c0);
    float bb[4] = {b2v.x, b2v.y, b2v.z, b2v.w};
    #pragma unroll
    for (int i = 0; i < 4; ++i){
        float4 o;
        o.x = silu_f(acc2[i][0] + bb[0]);
        o.y = silu_f(acc2[i][1] + bb[1]);
        o.z = silu_f(acc2[i][2] + bb[2]);
        o.w = silu_f(acc2[i][3] + bb[3]);
        *(float4*)(hA + (size_t)(n0 + r0 + i) * 128 + c0) = o;
    }
}

// ---------------- edge message MLP (MFMA bf16) + scatter-add ----------------
__global__ __launch_bounds__(256) void k_edge_m(const float* __restrict__ hA, const float* __restrict__ x,
                                                const float* __restrict__ p, const float* __restrict__ vars,
                                                const int* __restrict__ esrc, const int* __restrict__ edst,
                                                const __bf16* __restrict__ Wp1, const float* __restrict__ bias1,
                                                const __bf16* __restrict__ Wp2, const float* __restrict__ bias2,
                                                float* __restrict__ agg){
    __shared__ __align__(16) __bf16 sA1[9 * 2 * 64 * 8];   // 9216 hw = 18 KB
    __shared__ __align__(16) __bf16 sA2[4 * 2 * 64 * 8];   // 4096 hw = 8 KB
    __shared__ int sdst[32], ssrc[32];
    int tid = threadIdx.x;
    int e0 = blockIdx.x * 32;
    if (tid < 32){ sdst[tid] = edst[e0 + tid]; ssrc[tid] = esrc[e0 + tid]; }
    __syncthreads();
    // gather h[dst] (k 0..127) and h[src] (k 128..255)
    for (int i = tid; i < 32 * 64; i += 256){
        int e = i >> 6, rest = i & 63, which = rest >> 5, chunk = rest & 31;
        int node = which ? ssrc[e] : sdst[e];
        float4 v = *(const float4*)(hA + (size_t)node * 128 + chunk * 4);
        int k = which * 128 + chunk * 4;
        bf16x4 o;
        o[0] = (__bf16)v.x; o[1] = (__bf16)v.y; o[2] = (__bf16)v.z; o[3] = (__bf16)v.w;
        *(bf16x4*)(sA1 + apos(e, k)) = o;
    }
    // tail features k = 256..287 (xdiff 25, pdiff 1, vars[dst] 4, pad 2)
    for (int i = tid; i < 32 * 32; i += 256){
        int e = i >> 5, kk = i & 31;
        int d = sdst[e], s = ssrc[e];
        float v;
        if (kk < 25)       v = x[d * 25 + kk] - x[s * 25 + kk];
        else if (kk == 25) v = p[d] - p[s];
        else if (kk < 30)  v = vars[d * 4 + (kk - 26)];
        else               v = 0.0f;
        sA1[apos(e, 256 + kk)] = (__bf16)v;
    }
    __syncthreads();
    int w = tid >> 6, lane = tid & 63;
    int cb0 = w * 2;
    int clo = lane & 15, rhi = lane >> 4;
    f32x4 z = {0.f, 0.f, 0.f, 0.f};
    f32x4 acc[2][2] = {{z, z}, {z, z}};
    #pragma unroll
    for (int kb = 0; kb < 9; ++kb){
        bf16x8 a0 = *(bf16x8*)(sA1 + ((kb * 2 + 0) * 64 + lane) * 8);
        bf16x8 a1 = *(bf16x8*)(sA1 + ((kb * 2 + 1) * 64 + lane) * 8);
        bf16x8 w0 = *(const bf16x8*)(Wp1 + (size_t)((kb * 8 + cb0) * 64 + lane) * 8);
        bf16x8 w1 = *(const bf16x8*)(Wp1 + (size_t)((kb * 8 + cb0 + 1) * 64 + lane) * 8);
        acc[0][0] = mfma16(a0, w0, acc[0][0]);
        acc[0][1] = mfma16(a0, w1, acc[0][1]);
        acc[1][0] = mfma16(a1, w0, acc[1][0]);
        acc[1][1] = mfma16(a1, w1, acc[1][1]);
    }
    // y1 = silu(acc + b1) -> sA2 (A-pack for GEMM2, k = col)
    #pragma unroll
    for (int nf = 0; nf < 2; ++nf){
        int col = (cb0 + nf) * 16 + clo;
        float bv = bias1[col];
        #pragma unroll
        for (int mt = 0; mt < 2; ++mt)
            #pragma unroll
            for (int i = 0; i < 4; ++i){
                int e = mt * 16 + rhi * 4 + i;
                float v = silu_f(acc[mt][nf][i] + bv);
                sA2[apos(e, col)] = (__bf16)v;
            }
    }
    __syncthreads();
    f32x4 acc2[2][2] = {{z, z}, {z, z}};
    #pragma unroll
    for (int kb = 0; kb < 4; ++kb){
        bf16x8 a0 = *(bf16x8*)(sA2 + ((kb * 2 + 0) * 64 + lane) * 8);
        bf16x8 a1 = *(bf16x8*)(sA2 + ((kb * 2 + 1) * 64 + lane) * 8);
        bf16x8 w0 = *(const bf16x8*)(Wp2 + (size_t)((kb * 8 + cb0) * 64 + lane) * 8);
        bf16x8 w1 = *(const bf16x8*)(Wp2 + (size_t)((kb * 8 + cb0 + 1) * 64 + lane) * 8);
        acc2[0][0] = mfma16(a0, w0, acc2[0][0]);
        acc2[0][1] = mfma16(a0, w1, acc2[0][1]);
        acc2[1][0] = mfma16(a1, w0, acc2[1][0]);
        acc2[1][1] = mfma16(a1, w1, acc2[1][1]);
    }
    #pragma unroll
    for (int nf = 0; nf < 2; ++nf){
        int col = (cb0 + nf) * 16 + clo;
        float bv = bias2[col];
        #pragma unroll
        for (int mt = 0; mt < 2; ++mt)
            #pragma unroll
            for (int i = 0; i < 4; ++i){
                int e = mt * 16 + rhi * 4 + i;
                float v = silu_f(acc2[mt][nf][i] + bv);
                atomicAdd(agg + (size_t)sdst[e] * 128 + col, v);
            }
    }
}

// ---------------- node update MLP (MFMA bf16), h += u ----------------
__global__ __launch_bounds__(256) void k_upd_m(float* __restrict__ hA, const float* __restrict__ agg,
                                               const float* __restrict__ vars, const float* __restrict__ invdeg,
                                               const __bf16* __restrict__ Wp1, const float* __restrict__ bias1,
                                               const __bf16* __restrict__ Wp2, const float* __restrict__ bias2){
    __shared__ __align__(16) __bf16 sA1[9 * 2 * 64 * 8];
    __shared__ __align__(16) __bf16 sA2[4 * 2 * 64 * 8];
    int tid = threadIdx.x;
    int n0 = blockIdx.x * 32;
    for (int i = tid; i < 32 * 64; i += 256){
        int e = i >> 6, rest = i & 63, which = rest >> 5, chunk = rest & 31;
        int node = n0 + e;
        float4 v;
        if (which == 0){
            v = *(const float4*)(hA + (size_t)node * 128 + chunk * 4);
        } else {
            v = *(const float4*)(agg + (size_t)node * 128 + chunk * 4);
            float s = invdeg[node];
            v.x *= s; v.y *= s; v.z *= s; v.w *= s;
        }
        int k = which * 128 + chunk * 4;
        bf16x4 o;
        o[0] = (__bf16)v.x; o[1] = (__bf16)v.y; o[2] = (__bf16)v.z; o[3] = (__bf16)v.w;
        *(bf16x4*)(sA1 + apos(e, k)) = o;
    }
    for (int i = tid; i < 32 * 32; i += 256){
        int e = i >> 5, kk = i & 31;
        float v = (kk < 4) ? vars[(size_t)(n0 + e) * 4 + kk] : 0.0f;
        sA1[apos(e, 256 + kk)] = (__bf16)v;
    }
    __syncthreads();
    int w = tid >> 6, lane = tid & 63;
    int cb0 = w * 2;
    int clo = lane & 15, rhi = lane >> 4;
    f32x4 z = {0.f, 0.f, 0.f, 0.f};
    f32x4 acc[2][2] = {{z, z}, {z, z}};
    #pragma unroll
    for (int kb = 0; kb < 9; ++kb){
        bf16x8 a0 = *(bf16x8*)(sA1 + ((kb * 2 + 0) * 64 + lane) * 8);
        bf16x8 a1 = *(bf16x8*)(sA1 + ((kb * 2 + 1) * 64 + lane) * 8);
        bf16x8 w0 = *(const bf16x8*)(Wp1 + (size_t)((kb * 8 + cb0) * 64 + lane) * 8);
        bf16x8 w1 = *(const bf16x8*)(Wp1 + (size_t)((kb * 8 + cb0 + 1) * 64 + lane) * 8);
        acc[0][0] = mfma16(a0, w0, acc[0][0]);
        acc[0][1] = mfma16(a0, w1, acc[0][1]);
        acc[1][0] = mfma16(a1, w0, acc[1][0]);
        acc[1][1] = mfma16(a1, w1, acc[1][1]);
    }
    #pragma unroll
    for (int nf = 0; nf < 2; ++nf){
        int col = (cb0 + nf) * 16 + clo;
        float bv = bias1[col];
        #pragma unroll
        for (int mt = 0; mt < 2; ++mt)
            #pragma unroll
            for (int i = 0; i < 4; ++i){
                int e = mt * 16 + rhi * 4 + i;
                float v = silu_f(acc[mt][nf][i] + bv);
                sA2[apos(e, col)] = (__bf16)v;
            }
    }
    __syncthreads();
    f32x4 acc2[2][2] = {{z, z}, {z, z}};
    #pragma unroll
    for (int kb = 0; kb < 4; ++kb){
        bf16x8 a0 = *(bf16x8*)(sA2 + ((kb * 2 + 0) * 64 + lane) * 8);
        bf16x8 a1 = *(bf16x8*)(sA2 + ((kb * 2 + 1) * 64 + lane) * 8);
        bf16x8 w0 = *(const bf16x8*)(Wp2 + (size_t)((kb * 8 + cb0) * 64 + lane) * 8);
        bf16x8 w1 = *(const bf16x8*)(Wp2 + (size_t)((kb * 8 + cb0 + 1) * 64 + lane) * 8);
        acc2[0][0] = mfma16(a0, w0, acc2[0][0]);
        acc2[0][1] = mfma16(a0, w1, acc2[0][1]);
        acc2[1][0] = mfma16(a1, w0, acc2[1][0]);
        acc2[1][1] = mfma16(a1, w1, acc2[1][1]);
    }
    #pragma unroll
    for (int nf = 0; nf < 2; ++nf){
        int col = (cb0 + nf) * 16 + clo;
        float bv = bias2[col];
        #pragma unroll
        for (int mt = 0; mt < 2; ++mt)
            #pragma unroll
            for (int i = 0; i < 4; ++i){
                int e = mt * 16 + rhi * 4 + i;
                size_t idx = (size_t)(n0 + e) * 128 + col;
                float u = silu_f(acc2[mt][nf][i] + bv);
                hA[idx] = hA[idx] + u;   // each (node,col) owned by exactly one thread
            }
    }
}

// ---------------- layernorm stats (two-stage, deterministic) ----------------
__global__ __launch_bounds__(256) void k_stats1(const float* __restrict__ h,
                                                float* __restrict__ psum, float* __restrict__ psq){
    __shared__ float s1[256], s2[256];
    int tid = threadIdx.x;
    int c = tid & 127, half = tid >> 7;
    int rbase = blockIdx.x * 256 + half * 128;
    float s = 0.0f, q = 0.0f;
    for (int r = 0; r < 128; ++r){
        float v = h[(size_t)(rbase + r) * 128 + c];
        s += v; q += v * v;
    }
    s1[tid] = s; s2[tid] = q;
    __syncthreads();
    if (half == 0){
        psum[blockIdx.x * 128 + c] = s1[tid] + s1[tid + 128];
        psq [blockIdx.x * 128 + c] = s2[tid] + s2[tid + 128];
    }
}

__global__ __launch_bounds__(128) void k_stats2(const float* __restrict__ psum, const float* __restrict__ psq,
                                                float* __restrict__ mu, float* __restrict__ istd){
    int c = threadIdx.x;
    float s = 0.0f, q = 0.0f;
    for (int b = 0; b < 256; ++b){ s += psum[b * 128 + c]; q += psq[b * 128 + c]; }
    float m = s * (1.0f / N_NODES);
    float v = q * (1.0f / N_NODES) - m * m;
    mu[c] = m;
    istd[c] = rsqrtf(v + EPS_F);
}

__global__ __launch_bounds__(256) void k_ln(float* __restrict__ h, const float* __restrict__ mu,
                                            const float* __restrict__ istd){
    int idx = blockIdx.x * 256 + threadIdx.x;
    int c4 = idx & 31;
    float4 v = *(float4*)(h + (size_t)idx * 4);
    float4 m = *(const float4*)(mu + c4 * 4);
    float4 sd = *(const float4*)(istd + c4 * 4);
    v.x = (v.x - m.x) * sd.x;
    v.y = (v.y - m.y) * sd.y;
    v.z = (v.z - m.z) * sd.z;
    v.w = (v.w - m.w) * sd.w;
    *(float4*)(h + (size_t)idx * 4) = v;
}

// ---------------- decoder conv + output ----------------
__global__ __launch_bounds__(256) void k_dec(const float* __restrict__ h, const float* __restrict__ x,
                                             const float* __restrict__ dt,
                                             const float* __restrict__ W1, const float* __restrict__ b1,
                                             const float* __restrict__ W2, const float* __restrict__ b2,
                                             float* __restrict__ out){
    __shared__ __align__(16) float sh[8 * 128];
    __shared__ float so[8 * 308];
    __shared__ float sw1[128], sw2[112], sb1[8];
    int tid = threadIdx.x;
    int n0 = blockIdx.x * 8;
    for (int i = tid; i < 8 * 32; i += 256){
        int e = i >> 5, chunk = i & 31;
        *(float4*)(sh + e * 128 + chunk * 4) = *(const float4*)(h + (size_t)(n0 + e) * 128 + chunk * 4);
    }
    if (tid < 128) sw1[tid] = W1[tid];
    else if (tid < 240) sw2[tid - 128] = W2[tid - 128];
    if (tid < 8) sb1[tid] = b1[tid];
    __syncthreads();
    int g = tid >> 5, lane = tid & 31;
    int node = n0 + g;
    for (int idx = lane; idx < 304; idx += 32){
        int c = idx / 38, j = idx % 38;
        float a = sb1[c];
        int base = 3 * j;
        #pragma unroll
        for (int k = 0; k < 16; ++k) a = fmaf(sh[g * 128 + base + k], sw1[c * 16 + k], a);
        so[g * 308 + c * 38 + j] = silu_f(a);
    }
    __syncthreads();
    if (lane < 25){
        float a = b2[0];
        #pragma unroll
        for (int c = 0; c < 8; ++c)
            #pragma unroll
            for (int k = 0; k < 14; ++k)
                a = fmaf(so[g * 308 + c * 38 + lane + k], sw2[c * 14 + k], a);
        float dtv = dt[0];
        out[(size_t)node * 25 + lane] = x[(size_t)node * 25 + 24] + dtv * (float)(lane + 1) * a;
    }
}

extern "C" void kernel_launch(void* const* d_in, const int* in_sizes, int n_in,
                              void* d_out, int out_size, void* d_ws, size_t ws_size,
                              hipStream_t stream){
    (void)in_sizes; (void)n_in; (void)out_size; (void)ws_size;
    const float* x      = (const float*)d_in[0];
    const float* pos    = (const float*)d_in[1];
    const float* vars   = (const float*)d_in[2];
    const float* dt     = (const float*)d_in[3];
    const int*   ei     = (const int*)d_in[4];
    const float* encW1  = (const float*)d_in[5];
    const float* encb1  = (const float*)d_in[6];
    const float* encW2  = (const float*)d_in[7];
    const float* encb2  = (const float*)d_in[8];
    const float* msgW1  = (const float*)d_in[9];
    const float* msgb1  = (const float*)d_in[10];
    const float* msgW2  = (const float*)d_in[11];
    const float* msgb2  = (const float*)d_in[12];
    const float* updW1  = (const float*)d_in[13];
    const float* updb1  = (const float*)d_in[14];
    const float* updW2  = (const float*)d_in[15];
    const float* updb2  = (const float*)d_in[16];
    const float* decW1  = (const float*)d_in[17];
    const float* decb1  = (const float*)d_in[18];
    const float* decW2  = (const float*)d_in[19];
    const float* decb2  = (const float*)d_in[20];
    float* out = (float*)d_out;

    float* ws = (float*)d_ws;
    size_t off = 0;
    float* hA     = ws + off; off += (size_t)N_NODES * 128;
    float* agg    = ws + off; off += (size_t)N_NODES * 128;
    float* p      = ws + off; off += N_NODES;
    float* invdeg = ws + off; off += N_NODES;
    float* psum   = ws + off; off += 256 * 128;
    float* psq    = ws + off; off += 256 * 128;
    float* muA    = ws + off; off += 128;
    float* istdA  = ws + off; off += 128;
    int* deg      = (int*)(ws + off); off += N_NODES;
    unsigned* maxp = (unsigned*)(ws + off); off += 2;
    __bf16* wpack = (__bf16*)(ws + off); off += (PK_TOTAL + 1) / 2;

    __bf16* pm1 = wpack;
    __bf16* pm2 = pm1 + PK_MSG1;
    __bf16* pu1 = pm2 + PK_MSG2;
    __bf16* pu2 = pu1 + PK_UPD1;

    const int* esrc = ei;
    const int* edst = ei + N_EDGES;

    hipMemsetAsync(deg, 0, (size_t)N_NODES * sizeof(int) + sizeof(unsigned), stream);

    k_pack<<<(PK_TOTAL + 255) / 256, 256, 0, stream>>>(msgW1, msgW2, updW1, updW2, wpack);
    k_max<<<256, 256, 0, stream>>>(pos, maxp);
    k_deg<<<N_EDGES / 256, 256, 0, stream>>>(edst, deg);
    k_prep<<<N_NODES / 256, 256, 0, stream>>>(pos, maxp, deg, p, invdeg);
    k_enc<<<N_NODES / 32, 256, 0, stream>>>(x, p, vars, encW1, encb1, encW2, encb2, hA);

    for (int l = 0; l < N_LAYERS; ++l){
        hipMemsetAsync(agg, 0, (size_t)N_NODES * 128 * sizeof(float), stream);
        k_edge_m<<<N_EDGES / 32, 256, 0, stream>>>(hA, x, p, vars, esrc, edst,
            pm1 + (size_t)l * 36864, msgb1 + l * 128,
            pm2 + (size_t)l * 16384, msgb2 + l * 128, agg);
        k_upd_m<<<N_NODES / 32, 256, 0, stream>>>(hA, agg, vars, invdeg,
            pu1 + (size_t)l * 36864, updb1 + l * 128,
            pu2 + (size_t)l * 16384, updb2 + l * 128);
        k_stats1<<<256, 256, 0, stream>>>(hA, psum, psq);
        k_stats2<<<1, 128, 0, stream>>>(psum, psq, muA, istdA);
        k_ln<<<8192, 256, 0, stream>>>(hA, muA, istdA);
    }

    k_dec<<<N_NODES / 8, 256, 0, stream>>>(hA, x, dt, decW1, decb1, decW2, decb2, out);
}